// Round 1
// baseline (471.040 us; speedup 1.0000x reference)
//
#include <hip/hip_runtime.h>

#define NQ 10
#define DEPTH 4
#define NS (1 << NQ)          // 1024 amplitudes
#define NGATES (DEPTH * NQ)   // 40 Rot gates

// ---------------------------------------------------------------------------
// Precompute the 40 Rot(phi,theta,omega) 2x2 complex matrices (batch-uniform)
// PennyLane Rot = RZ(omega) RY(theta) RZ(phi):
//   m00 = e^{-i(phi+omega)/2} cos(theta/2)
//   m01 = -e^{+i(phi-omega)/2} sin(theta/2)
//   m10 = e^{-i(phi-omega)/2} sin(theta/2)
//   m11 = e^{+i(phi+omega)/2} cos(theta/2)
// Layout in ws: gate g -> 8 floats [m00r,m00i, m01r,m01i, m10r,m10i, m11r,m11i]
// ---------------------------------------------------------------------------
__global__ void qgate_precompute(const float* __restrict__ qw,
                                 float* __restrict__ gates) {
    int g = blockIdx.x * blockDim.x + threadIdx.x;
    if (g >= NGATES) return;
    float phi   = qw[g * 3 + 0];
    float theta = qw[g * 3 + 1];
    float omega = qw[g * 3 + 2];
    float s, c;   sincosf(0.5f * theta, &s, &c);
    float sa, ca; sincosf(0.5f * (phi + omega), &sa, &ca);
    float sb, cb; sincosf(0.5f * (phi - omega), &sb, &cb);
    float* o = gates + g * 8;
    o[0] =  c * ca;  o[1] = -c * sa;   // m00
    o[2] = -s * cb;  o[3] = -s * sb;   // m01
    o[4] =  s * cb;  o[5] = -s * sb;   // m10
    o[6] =  c * ca;  o[7] =  c * sa;   // m11
}

// ---------------------------------------------------------------------------
// One block (256 threads) simulates one batch element. State lives in LDS.
// Flat index convention (from reference einsum build order):
//   qubit w occupies bit position p = NQ-1-w  (qubit 0 = MSB).
// ---------------------------------------------------------------------------
__global__ __launch_bounds__(256) void qsim_kernel(
        const float* __restrict__ inp,    // (B, NQ)
        const float* __restrict__ gates,  // (NGATES, 8)
        float* __restrict__ out) {        // (B, NQ)
    __shared__ float sre[NS];
    __shared__ float sim[NS];
    __shared__ float gmat[NGATES * 8];
    __shared__ float cw[NQ], sw[NQ];

    const int tid = threadIdx.x;
    const int b = blockIdx.x;

    // cache gate matrices (320 floats) in LDS
    for (int i = tid; i < NGATES * 8; i += 256) gmat[i] = gates[i];
    // per-qubit RY embedding factors
    if (tid < NQ) {
        float x = inp[b * NQ + tid];
        float ss, cc; sincosf(0.5f * x, &ss, &cc);
        cw[tid] = cc; sw[tid] = ss;
    }
    __syncthreads();

    // ---- init product state: amp[k] = prod_w (bit_w ? sin : cos), real ----
    #pragma unroll
    for (int jj = 0; jj < 4; ++jj) {
        int k = tid + (jj << 8);
        float a = 1.0f;
        #pragma unroll
        for (int w = 0; w < NQ; ++w) {
            int bit = (k >> (NQ - 1 - w)) & 1;
            a *= bit ? sw[w] : cw[w];
        }
        sre[k] = a; sim[k] = 0.0f;
    }
    __syncthreads();

    // ---- layers ----
    for (int l = 0; l < DEPTH; ++l) {
        // per-wire Rot gates: 512 disjoint pairs, 2 per thread
        for (int w = 0; w < NQ; ++w) {
            const float* m = &gmat[(l * NQ + w) * 8];
            const float m00r = m[0], m00i = m[1], m01r = m[2], m01i = m[3];
            const float m10r = m[4], m10i = m[5], m11r = m[6], m11i = m[7];
            const int p = NQ - 1 - w;
            const int pm = 1 << p;
            #pragma unroll
            for (int jj = 0; jj < 2; ++jj) {
                int j = tid + (jj << 8);                       // pair id in [0,512)
                int k0 = ((j >> p) << (p + 1)) | (j & (pm - 1));
                int k1 = k0 | pm;
                float a0r = sre[k0], a0i = sim[k0];
                float a1r = sre[k1], a1i = sim[k1];
                float n0r = m00r * a0r - m00i * a0i + m01r * a1r - m01i * a1i;
                float n0i = m00r * a0i + m00i * a0r + m01r * a1i + m01i * a1r;
                float n1r = m10r * a0r - m10i * a0i + m11r * a1r - m11i * a1i;
                float n1i = m10r * a0i + m10i * a0r + m11r * a1i + m11i * a1r;
                sre[k0] = n0r; sim[k0] = n0i;
                sre[k1] = n1r; sim[k1] = n1i;
            }
            __syncthreads();
        }
        // ring of CNOTs: control w -> target (w+r)%NQ, 256 disjoint swap pairs
        const int r = (l % (NQ - 1)) + 1;
        for (int w = 0; w < NQ; ++w) {
            const int t = (w + r) % NQ;
            const int pc = NQ - 1 - w;
            const int pt = NQ - 1 - t;
            const int plo = pc < pt ? pc : pt;
            const int phi = pc < pt ? pt : pc;
            int j = tid;                                       // pair id in [0,256)
            int t0 = ((j  >> plo) << (plo + 1)) | (j  & ((1 << plo) - 1));
            int t1 = ((t0 >> phi) << (phi + 1)) | (t0 & ((1 << phi) - 1));
            int k0 = t1 | (1 << pc);          // control=1, target=0
            int k1 = k0 | (1 << pt);          // control=1, target=1
            float ar = sre[k0], ai = sim[k0];
            float br = sre[k1], bi = sim[k1];
            sre[k0] = br; sim[k0] = bi;
            sre[k1] = ar; sim[k1] = ai;
            __syncthreads();
        }
    }

    // ---- measurement: <Z_w> = sum_k |amp[k]|^2 * (1 - 2*bit_w(k)) ----
    float acc[NQ];
    #pragma unroll
    for (int w = 0; w < NQ; ++w) acc[w] = 0.0f;
    #pragma unroll
    for (int jj = 0; jj < 4; ++jj) {
        int k = tid + (jj << 8);
        float pr = sre[k] * sre[k] + sim[k] * sim[k];
        #pragma unroll
        for (int w = 0; w < NQ; ++w) {
            int bit = (k >> (NQ - 1 - w)) & 1;
            acc[w] += bit ? -pr : pr;
        }
    }
    // 64-lane butterfly reduce
    #pragma unroll
    for (int w = 0; w < NQ; ++w) {
        #pragma unroll
        for (int off = 32; off > 0; off >>= 1)
            acc[w] += __shfl_xor(acc[w], off);
    }
    __syncthreads();   // all lanes done reading sre/sim; safe to reuse sre
    const int wave = tid >> 6;
    const int lane = tid & 63;
    if (lane == 0) {
        #pragma unroll
        for (int w = 0; w < NQ; ++w) sre[wave * NQ + w] = acc[w];
    }
    __syncthreads();
    if (tid < NQ) {
        float v = sre[tid] + sre[NQ + tid] + sre[2 * NQ + tid] + sre[3 * NQ + tid];
        out[b * NQ + tid] = v;
    }
}

extern "C" void kernel_launch(void* const* d_in, const int* in_sizes, int n_in,
                              void* d_out, int out_size, void* d_ws, size_t ws_size,
                              hipStream_t stream) {
    const float* inp = (const float*)d_in[0];       // (B, NQ) float32
    const float* qw  = (const float*)d_in[1];       // (DEPTH, NQ, 3) float32
    float* out = (float*)d_out;                     // (B, NQ) float32
    float* gates = (float*)d_ws;                    // NGATES*8 floats

    const int B = in_sizes[0] / NQ;

    qgate_precompute<<<1, 64, 0, stream>>>(qw, gates);
    qsim_kernel<<<B, 256, 0, stream>>>(inp, gates, out);
}

// Round 2
// 335.332 us; speedup vs baseline: 1.4047x; 1.4047x over previous
//
#include <hip/hip_runtime.h>

#define NQ 10
#define DEPTH 4
#define NGATES (DEPTH * NQ)

// ---------------------------------------------------------------------------
// Precompute the 40 Rot(phi,theta,omega) 2x2 complex matrices (batch-uniform)
// Layout: gate g -> 8 floats [m00r,m00i, m01r,m01i, m10r,m10i, m11r,m11i]
// ---------------------------------------------------------------------------
__global__ void qgate_precompute(const float* __restrict__ qw,
                                 float* __restrict__ gates) {
    int g = blockIdx.x * blockDim.x + threadIdx.x;
    if (g >= NGATES) return;
    float phi   = qw[g * 3 + 0];
    float theta = qw[g * 3 + 1];
    float omega = qw[g * 3 + 2];
    float s, c;   sincosf(0.5f * theta, &s, &c);
    float sa, ca; sincosf(0.5f * (phi + omega), &sa, &ca);
    float sb, cb; sincosf(0.5f * (phi - omega), &sb, &cb);
    float* o = gates + g * 8;
    o[0] =  c * ca;  o[1] = -c * sa;   // m00
    o[2] = -s * cb;  o[3] = -s * sb;   // m01
    o[4] =  s * cb;  o[5] = -s * sb;   // m10
    o[6] =  c * ca;  o[7] =  c * sa;   // m11
}

// ---------------------------------------------------------------------------
// Final CNOT ring (layer DEPTH-1) folded into measurement parity masks.
// Symbolic GF(2) evolution: bit p of permuted index = parity(k & mf[p]).
// ---------------------------------------------------------------------------
struct Masks { int m[NQ]; };
constexpr Masks compute_masks() {
    int mf[NQ] = {};
    for (int i = 0; i < NQ; ++i) mf[i] = 1 << i;
    const int r = ((DEPTH - 1) % (NQ - 1)) + 1;
    for (int w = 0; w < NQ; ++w) {
        int pc = NQ - 1 - w;
        int pt = NQ - 1 - ((w + r) % NQ);
        mf[pt] ^= mf[pc];
    }
    Masks out{};
    for (int q = 0; q < NQ; ++q) out.m[q] = mf[NQ - 1 - q];
    return out;
}
constexpr Masks FM = compute_masks();

// ---------------------------------------------------------------------------
// Cross-lane xor exchange. DPP for masks 1,2,8 (pure VALU), ds_swizzle for
// 4,16 (LDS pipe, conflict-free), shfl for 32.
// ---------------------------------------------------------------------------
template<int M>
__device__ __forceinline__ float lxor(float v) {
    int x = __float_as_int(v);
    int r;
    if constexpr (M == 1)       r = __builtin_amdgcn_update_dpp(x, x, 0xB1, 0xF, 0xF, false);  // quad_perm [1,0,3,2]
    else if constexpr (M == 2)  r = __builtin_amdgcn_update_dpp(x, x, 0x4E, 0xF, 0xF, false);  // quad_perm [2,3,0,1]
    else if constexpr (M == 8)  r = __builtin_amdgcn_update_dpp(x, x, 0x128, 0xF, 0xF, false); // row_ror:8
    else if constexpr (M == 4)  r = __builtin_amdgcn_ds_swizzle(x, 0x101F);                    // xor-4
    else if constexpr (M == 16) r = __builtin_amdgcn_ds_swizzle(x, 0x401F);                    // xor-16
    else                        r = __float_as_int(__shfl_xor(v, M, 64));
    return __int_as_float(r);
}

// --- Rot on a local qubit (bit P of the in-lane index, P in 0..3) ----------
template<int P>
__device__ __forceinline__ void rot_local(float* sr, float* si, const float* g) {
    const float m00r = g[0], m00i = g[1], m01r = g[2], m01i = g[3];
    const float m10r = g[4], m10i = g[5], m11r = g[6], m11i = g[7];
    #pragma unroll
    for (int i = 0; i < 16; ++i) {
        if ((i >> P) & 1) continue;
        const int j = i | (1 << P);
        float a0r = sr[i], a0i = si[i], a1r = sr[j], a1i = si[j];
        sr[i] = m00r*a0r - m00i*a0i + m01r*a1r - m01i*a1i;
        si[i] = m00r*a0i + m00i*a0r + m01r*a1i + m01i*a1r;
        sr[j] = m10r*a0r - m10i*a0i + m11r*a1r - m11i*a1i;
        si[j] = m10r*a0i + m10i*a0r + m11r*a1i + m11i*a1r;
    }
}

// --- Rot on a lane qubit (lane bit LB in 0..5) -----------------------------
// Lane with bit b: new = m[b][b]*self + m[b][1-b]*partner
template<int LB>
__device__ __forceinline__ void rot_lane(float* sr, float* si, const float* g, int lane) {
    const int b = (lane >> LB) & 1;
    const float cAr = b ? g[6] : g[0], cAi = b ? g[7] : g[1];
    const float cBr = b ? g[4] : g[2], cBi = b ? g[5] : g[3];
    #pragma unroll
    for (int i = 0; i < 16; ++i) {
        float pr = lxor<(1 << LB)>(sr[i]);
        float pi = lxor<(1 << LB)>(si[i]);
        float r = sr[i], im = si[i];
        sr[i] = cAr*r - cAi*im + cBr*pr - cBi*pi;
        si[i] = cAr*im + cAi*r + cBr*pi + cBi*pr;
    }
}

// --- CNOT variants ----------------------------------------------------------
template<int PC, int PT>   // both bits local: static permutation
__device__ __forceinline__ void cnot_ll(float* sr, float* si) {
    #pragma unroll
    for (int i = 0; i < 16; ++i) {
        if (((i >> PC) & 1) && !((i >> PT) & 1)) {
            const int j = i | (1 << PT);
            float tr = sr[i], ti = si[i];
            sr[i] = sr[j]; si[i] = si[j];
            sr[j] = tr;    si[j] = ti;
        }
    }
}

template<int PC, int TLB>  // control local, target lane: unconditional swap of half
__device__ __forceinline__ void cnot_loc_lane(float* sr, float* si) {
    #pragma unroll
    for (int i = 0; i < 16; ++i) {
        if ((i >> PC) & 1) {
            sr[i] = lxor<(1 << TLB)>(sr[i]);
            si[i] = lxor<(1 << TLB)>(si[i]);
        }
    }
}

template<int CLB, int PT>  // control lane, target local: per-lane select
__device__ __forceinline__ void cnot_lane_loc(float* sr, float* si, int lane) {
    const bool c = (lane >> CLB) & 1;
    #pragma unroll
    for (int i = 0; i < 16; ++i) {
        if (!((i >> PT) & 1)) {
            const int j = i | (1 << PT);
            float t0r = c ? sr[j] : sr[i], t0i = c ? si[j] : si[i];
            float t1r = c ? sr[i] : sr[j], t1i = c ? si[i] : si[j];
            sr[i] = t0r; si[i] = t0i; sr[j] = t1r; si[j] = t1i;
        }
    }
}

template<int CLB, int TLB> // both lane: exchange + select
__device__ __forceinline__ void cnot_lane_lane(float* sr, float* si, int lane) {
    const bool c = (lane >> CLB) & 1;
    #pragma unroll
    for (int i = 0; i < 16; ++i) {
        float xr = lxor<(1 << TLB)>(sr[i]);
        float xi = lxor<(1 << TLB)>(si[i]);
        sr[i] = c ? xr : sr[i];
        si[i] = c ? xi : si[i];
    }
}

// --- Sequencers -------------------------------------------------------------
template<int L, int W>
struct RotStep {
    static __device__ __forceinline__ void run(float* sr, float* si, const float* gates, int lane) {
        constexpr int P = NQ - 1 - W;
        const float* g = gates + (L * NQ + W) * 8;
        if constexpr (P < 4) rot_local<P>(sr, si, g);
        else                 rot_lane<P - 4>(sr, si, g, lane);
        RotStep<L, W + 1>::run(sr, si, gates, lane);
    }
};
template<int L>
struct RotStep<L, NQ> {
    static __device__ __forceinline__ void run(float*, float*, const float*, int) {}
};

template<int L, int W>
struct RingStep {
    static __device__ __forceinline__ void run(float* sr, float* si, int lane) {
        constexpr int R  = (L % (NQ - 1)) + 1;
        constexpr int T  = (W + R) % NQ;
        constexpr int PC = NQ - 1 - W;
        constexpr int PT = NQ - 1 - T;
        if constexpr (PC < 4 && PT < 4)      cnot_ll<PC, PT>(sr, si);
        else if constexpr (PC < 4)           cnot_loc_lane<PC, PT - 4>(sr, si);
        else if constexpr (PT < 4)           cnot_lane_loc<PC - 4, PT>(sr, si, lane);
        else                                 cnot_lane_lane<PC - 4, TLB_helper(PT)>(sr, si, lane);
    }
    static constexpr int TLB_helper(int pt) { return pt - 4; }
};
// (use a plain chain instead of the helper above for clarity)
template<int L, int W>
struct Ring {
    static __device__ __forceinline__ void run(float* sr, float* si, int lane) {
        constexpr int R  = (L % (NQ - 1)) + 1;
        constexpr int T  = (W + R) % NQ;
        constexpr int PC = NQ - 1 - W;
        constexpr int PT = NQ - 1 - T;
        if constexpr (PC < 4 && PT < 4)      cnot_ll<PC, PT>(sr, si);
        else if constexpr (PC < 4)           cnot_loc_lane<PC, PT - 4>(sr, si);
        else if constexpr (PT < 4)           cnot_lane_loc<PC - 4, PT>(sr, si, lane);
        else                                 cnot_lane_lane<PC - 4, PT - 4>(sr, si, lane);
        Ring<L, W + 1>::run(sr, si, lane);
    }
};
template<int L>
struct Ring<L, NQ> {
    static __device__ __forceinline__ void run(float*, float*, int) {}
};

// ---------------------------------------------------------------------------
// One wave per batch element. State: 16 complex amplitudes per lane.
// Amplitude index k = (lane << 4) | loc. Qubit w <-> bit 9-w.
//   qubits 0..5  -> lane bits 5..0 ; qubits 6..9 -> loc bits 3..0
// ---------------------------------------------------------------------------
__global__ __launch_bounds__(256) void qsim_kernel(
        const float* __restrict__ inp,
        const float* __restrict__ gates,
        float* __restrict__ out,
        int B) {
    const int lane = threadIdx.x & 63;
    int b = (blockIdx.x << 2) | (threadIdx.x >> 6);
    b = __builtin_amdgcn_readfirstlane(b);
    if (b >= B) return;

    // ---- init: RY embedding fused with layer-0 Rot --------------------------
    // lane factor: product over qubits 0..5 of their (a0|a1) component
    float Lr = 1.0f, Li = 0.0f;
    #pragma unroll
    for (int w = 0; w < 6; ++w) {
        const float* g = gates + w * 8;
        float x = inp[b * NQ + w];
        float s, c; sincosf(0.5f * x, &s, &c);
        float a0r = g[0]*c + g[2]*s, a0i = g[1]*c + g[3]*s;
        float a1r = g[4]*c + g[6]*s, a1i = g[5]*c + g[7]*s;
        int bit = (lane >> (5 - w)) & 1;
        float ar = bit ? a1r : a0r, ai = bit ? a1i : a0i;
        float nr = Lr*ar - Li*ai, ni = Lr*ai + Li*ar;
        Lr = nr; Li = ni;
    }
    // local product over qubits 6..9 (loc bits 3..0)
    float sr[16], si[16];
    {
        float qr[4][2], qi[4][2];
        #pragma unroll
        for (int j = 0; j < 4; ++j) {
            const int w = 6 + j;
            const float* g = gates + w * 8;
            float x = inp[b * NQ + w];
            float s, c; sincosf(0.5f * x, &s, &c);
            qr[j][0] = g[0]*c + g[2]*s; qi[j][0] = g[1]*c + g[3]*s;
            qr[j][1] = g[4]*c + g[6]*s; qi[j][1] = g[5]*c + g[7]*s;
        }
        #pragma unroll
        for (int loc = 0; loc < 16; ++loc) {
            float ar = Lr, ai = Li;
            #pragma unroll
            for (int j = 0; j < 4; ++j) {
                int bit = (loc >> (3 - j)) & 1;
                float br = qr[j][bit], bi = qi[j][bit];
                float nr = ar*br - ai*bi, ni = ar*bi + ai*br;
                ar = nr; ai = ni;
            }
            sr[loc] = ar; si[loc] = ai;
        }
    }

    // ---- circuit: ring0, rot1, ring1, rot2, ring2, rot3 (ring3 folded) -----
    Ring<0, 0>::run(sr, si, lane);
    RotStep<1, 0>::run(sr, si, gates, lane);
    Ring<1, 0>::run(sr, si, lane);
    RotStep<2, 0>::run(sr, si, gates, lane);
    Ring<2, 0>::run(sr, si, lane);
    RotStep<3, 0>::run(sr, si, gates, lane);

    // ---- measurement with final-ring parity masks ---------------------------
    float p[16];
    #pragma unroll
    for (int i = 0; i < 16; ++i) p[i] = sr[i]*sr[i] + si[i]*si[i];

    float z[NQ];
    #pragma unroll
    for (int q = 0; q < NQ; ++q) {
        const int m  = FM.m[q];
        const int ml = m & 15;
        const int mh = m >> 4;
        float s = 0.0f;
        #pragma unroll
        for (int i = 0; i < 16; ++i)
            s += (__builtin_popcount(i & ml) & 1) ? -p[i] : p[i];
        float v = (__builtin_popcount(lane & mh) & 1) ? -s : s;
        v += lxor<1>(v);  v += lxor<2>(v);  v += lxor<4>(v);
        v += lxor<8>(v);  v += lxor<16>(v); v += lxor<32>(v);
        z[q] = v;
    }
    if (lane == 0) {
        #pragma unroll
        for (int q = 0; q < NQ; ++q) out[b * NQ + q] = z[q];
    }
}

extern "C" void kernel_launch(void* const* d_in, const int* in_sizes, int n_in,
                              void* d_out, int out_size, void* d_ws, size_t ws_size,
                              hipStream_t stream) {
    const float* inp = (const float*)d_in[0];       // (B, NQ) float32
    const float* qw  = (const float*)d_in[1];       // (DEPTH, NQ, 3) float32
    float* out = (float*)d_out;                     // (B, NQ) float32
    float* gates = (float*)d_ws;                    // NGATES*8 floats

    const int B = in_sizes[0] / NQ;

    qgate_precompute<<<1, 64, 0, stream>>>(qw, gates);
    qsim_kernel<<<(B + 3) / 4, 256, 0, stream>>>(inp, gates, out, B);
}

// Round 3
// 136.839 us; speedup vs baseline: 3.4423x; 2.4506x over previous
//
#include <hip/hip_runtime.h>

#define NQ 10
#define DEPTH 4

typedef float f2 __attribute__((ext_vector_type(2)));

__device__ __forceinline__ f2 ff(float a, float b) { f2 r; r.x = a; r.y = b; return r; }
__device__ __forceinline__ f2 fsplat(float a) { return ff(a, a); }
__device__ __forceinline__ f2 rot90(f2 a) { return ff(-a.y, a.x); }   // i * a
__device__ __forceinline__ f2 ffma(f2 a, f2 b, f2 c) { return __builtin_elementwise_fma(a, b, c); }
__device__ __forceinline__ f2 cmul(f2 a, f2 b) { return ffma(fsplat(a.x), b, fsplat(a.y) * rot90(b)); }

// ---------------------------------------------------------------------------
// Compile-time GF(2) frame tracking. Storage index s (10 bits); logical index
// k = A s. Rot on logical qubit q pairs storage s and s^v (v = col q of A^-1),
// sign bit = parity(s & row_q(A)). CNOT rings fold into A entirely.
// Conventions (validated in rounds 1-2): qubit w <-> bit 9-w;
// ring l: r = l%9+1, gates w=0..9 sequential; composition N = T0 T1 ... T9;
// after ring: A <- N^-1 A (row ops in w order), A^-1 <- A^-1 N (col ops).
// ---------------------------------------------------------------------------
struct GateTab {
    unsigned v[DEPTH][NQ];
    unsigned r[DEPTH][NQ];
    unsigned mr[NQ];
};

constexpr GateTab build_tab() {
    GateTab t{};
    unsigned A[NQ], B[NQ];
    for (int p = 0; p < NQ; ++p) { A[p] = 1u << p; B[p] = 1u << p; }
    for (int l = 0; l < DEPTH; ++l) {
        for (int w = 0; w < NQ; ++w) {
            int q = NQ - 1 - w;
            unsigned v = 0;
            for (int p = 0; p < NQ; ++p) v |= ((B[p] >> q) & 1u) << p;
            t.v[l][w] = v;
            t.r[l][w] = A[q];
        }
        int r = (l % (NQ - 1)) + 1;
        for (int w = 0; w < NQ; ++w) {
            int pc = NQ - 1 - w;
            int pt = NQ - 1 - ((w + r) % NQ);
            A[pt] ^= A[pc];
        }
        for (int w = 0; w < NQ; ++w) {
            int pc = NQ - 1 - w;
            int pt = NQ - 1 - ((w + r) % NQ);
            for (int i = 0; i < NQ; ++i) B[i] ^= ((B[i] >> pt) & 1u) << pc;
        }
    }
    for (int i = 0; i < NQ; ++i) t.mr[i] = A[NQ - 1 - i];
    return t;
}
constexpr GateTab TAB = build_tab();

constexpr int msb4(unsigned x) { return (x & 8u) ? 3 : ((x & 4u) ? 2 : ((x & 2u) ? 1 : 0)); }

// ---------------------------------------------------------------------------
// Cross-lane xor exchange: DPP for 1,2,8 (VALU); ds_swizzle for any mask <32;
// shfl_xor (bpermute) for masks involving lane bit 5.
// ---------------------------------------------------------------------------
template<unsigned M>
__device__ __forceinline__ float lxf(float v) {
    if constexpr (M == 1u)
        return __int_as_float(__builtin_amdgcn_update_dpp(__float_as_int(v), __float_as_int(v), 0xB1, 0xF, 0xF, false));
    else if constexpr (M == 2u)
        return __int_as_float(__builtin_amdgcn_update_dpp(__float_as_int(v), __float_as_int(v), 0x4E, 0xF, 0xF, false));
    else if constexpr (M == 8u)
        return __int_as_float(__builtin_amdgcn_update_dpp(__float_as_int(v), __float_as_int(v), 0x128, 0xF, 0xF, false));
    else if constexpr (M < 32u)
        return __int_as_float(__builtin_amdgcn_ds_swizzle(__float_as_int(v), (int)((M << 10) | 0x1Fu)));
    else
        return __shfl_xor(v, (int)M, 64);
}
template<unsigned M>
__device__ __forceinline__ f2 exch(f2 v) { return ff(lxf<M>(v.x), lxf<M>(v.y)); }

// new = m00r*s + a*(i*s) + b*o + m01i*(i*o)   where (a,b) = ±(m00i, m01r)
// b=0: m00*s + m01*o ; b=1 (a,b negated): conj(m00)*s - conj(m01)*o = m11*s + m10*o
__device__ __forceinline__ f2 upd(f2 s, f2 o, float m00r, float a, float b, float m01i) {
    return ffma(fsplat(m00r), s,
           ffma(fsplat(a), rot90(s),
           ffma(fsplat(b), o, fsplat(m01i) * rot90(o))));
}

template<int L, int W>
__device__ __forceinline__ void gate(f2* s, const float4* gm, int lane) {
    constexpr unsigned V = TAB.v[L][W], R = TAB.r[L][W];
    constexpr unsigned VL = V & 15u, VH = V >> 4;
    constexpr unsigned RL = R & 15u, RH = R >> 4;
    const float4 mm = gm[L * NQ + W];
    const float m00r = mm.x, m01i = mm.w;
    float alpha = mm.y, beta = mm.z;
    if constexpr (RH != 0u) {
        unsigned pl31 = (unsigned)(__builtin_popcount((unsigned)lane & RH) & 1) << 31;
        alpha = __uint_as_float(__float_as_uint(alpha) ^ pl31);
        beta  = __uint_as_float(__float_as_uint(beta)  ^ pl31);
    }
    if constexpr (VH == 0u) {
        constexpr int PV = 1 << msb4(VL);
        #pragma unroll
        for (int i = 0; i < 16; ++i) {
            if (i & PV) continue;
            const int j = i ^ (int)VL;
            const bool fi = __builtin_popcount((unsigned)i & RL) & 1;
            const bool fj = __builtin_popcount((unsigned)j & RL) & 1;
            f2 ni = upd(s[i], s[j], m00r, fi ? -alpha : alpha, fi ? -beta : beta, m01i);
            f2 nj = upd(s[j], s[i], m00r, fj ? -alpha : alpha, fj ? -beta : beta, m01i);
            s[i] = ni; s[j] = nj;
        }
    } else if constexpr (VL == 0u) {
        #pragma unroll
        for (int i = 0; i < 16; ++i) {
            const bool fi = __builtin_popcount((unsigned)i & RL) & 1;
            f2 p = exch<VH>(s[i]);   // lockstep: reads pre-update values in all lanes
            s[i] = upd(s[i], p, m00r, fi ? -alpha : alpha, fi ? -beta : beta, m01i);
        }
    } else {
        constexpr int PV = 1 << msb4(VL);
        #pragma unroll
        for (int i = 0; i < 16; ++i) {
            if (i & PV) continue;
            const int j = i ^ (int)VL;
            const bool fi = __builtin_popcount((unsigned)i & RL) & 1;
            const bool fj = __builtin_popcount((unsigned)j & RL) & 1;
            f2 pj = exch<VH>(s[j]);  // partner value for amp i
            f2 pi = exch<VH>(s[i]);  // partner value for amp j
            f2 ni = upd(s[i], pj, m00r, fi ? -alpha : alpha, fi ? -beta : beta, m01i);
            f2 nj = upd(s[j], pi, m00r, fj ? -alpha : alpha, fj ? -beta : beta, m01i);
            s[i] = ni; s[j] = nj;
        }
    }
}

template<int L, int W> struct Seq {
    static __device__ __forceinline__ void run(f2* s, const float4* gm, int lane) {
        gate<L, W>(s, gm, lane);
        Seq<L, W + 1>::run(s, gm, lane);
    }
};
template<int L> struct Seq<L, NQ> {
    static __device__ __forceinline__ void run(f2*, const float4*, int) {}
};

// ---------------------------------------------------------------------------
// Rot matrix precompute: gate g -> float4 {m00r, m00i, m01r, m01i}
// (m11 = conj(m00), m10 = -conj(m01) are implicit.)
// ---------------------------------------------------------------------------
__global__ void qgate_precompute(const float* __restrict__ qw, float* __restrict__ gates) {
    int g = blockIdx.x * blockDim.x + threadIdx.x;
    if (g >= DEPTH * NQ) return;
    float phi = qw[g * 3 + 0], theta = qw[g * 3 + 1], omega = qw[g * 3 + 2];
    float s, c;   sincosf(0.5f * theta, &s, &c);
    float sa, ca; sincosf(0.5f * (phi + omega), &sa, &ca);
    float sb, cb; sincosf(0.5f * (phi - omega), &sb, &cb);
    ((float4*)gates)[g] = make_float4(c * ca, -c * sa, -s * cb, -s * sb);
}

// ---------------------------------------------------------------------------
// One wave per batch element; 16 complex amps (f2) per lane.
// s index i = loc (bits 3..0); lane bits 5..0 = storage bits 9..4.
// ---------------------------------------------------------------------------
__global__ __launch_bounds__(256) void qsim_kernel(
        const float* __restrict__ inp,
        const float* __restrict__ gates,
        float* __restrict__ out,
        int B) {
    const int lane = threadIdx.x & 63;
    int b = (blockIdx.x << 2) | (threadIdx.x >> 6);
    b = __builtin_amdgcn_readfirstlane(b);
    if (b >= B) return;
    const float4* gm = (const float4*)gates;

    // ---- embedding fused with layer-0 Rot; lane w<10 computes qubit w ----
    float x = (lane < NQ) ? inp[b * NQ + lane] : 0.0f;
    float sn, cn;
    sincosf(0.5f * x, &sn, &cn);
    float a0r = 0.f, a0i = 0.f, a1r = 0.f, a1i = 0.f;
    if (lane < NQ) {
        float4 mm = gm[lane];
        a0r = mm.x * cn + mm.z * sn;
        a0i = mm.y * cn + mm.w * sn;
        a1r = -mm.z * cn + mm.x * sn;
        a1i =  mm.w * cn - mm.y * sn;
    }
    // lane factor: qubits 0..5 <-> lane bits 5..0
    f2 L;
    {
        float r0 = __shfl(a0r, 0, 64), i0 = __shfl(a0i, 0, 64);
        float r1 = __shfl(a1r, 0, 64), i1 = __shfl(a1i, 0, 64);
        int bit = (lane >> 5) & 1;
        L = ff(bit ? r1 : r0, bit ? i1 : i0);
    }
    #pragma unroll
    for (int w = 1; w < 6; ++w) {
        float r0 = __shfl(a0r, w, 64), i0 = __shfl(a0i, w, 64);
        float r1 = __shfl(a1r, w, 64), i1 = __shfl(a1i, w, 64);
        int bit = (lane >> (5 - w)) & 1;
        L = cmul(L, ff(bit ? r1 : r0, bit ? i1 : i0));
    }
    // local factors: qubits 6..9 <-> loc bits 3..0
    f2 A0[4], A1[4];
    #pragma unroll
    for (int j = 0; j < 4; ++j) {
        A0[j] = ff(__shfl(a0r, 6 + j, 64), __shfl(a0i, 6 + j, 64));
        A1[j] = ff(__shfl(a1r, 6 + j, 64), __shfl(a1i, 6 + j, 64));
    }
    f2 s[16];
    {
        f2 t01[4], t23[4], lt[4];
        #pragma unroll
        for (int i = 0; i < 4; ++i) {
            t01[i] = cmul((i & 2) ? A1[0] : A0[0], (i & 1) ? A1[1] : A0[1]);
            t23[i] = cmul((i & 2) ? A1[2] : A0[2], (i & 1) ? A1[3] : A0[3]);
        }
        #pragma unroll
        for (int i = 0; i < 4; ++i) lt[i] = cmul(L, t01[i]);
        #pragma unroll
        for (int i = 0; i < 16; ++i) s[i] = cmul(lt[i >> 2], t23[i & 3]);
    }

    // ---- layers 1..3 (all CNOT rings folded into frames) ----
    Seq<1, 0>::run(s, gm, lane);
    Seq<2, 0>::run(s, gm, lane);
    Seq<3, 0>::run(s, gm, lane);

    // ---- measurement: local 16-pt WHT, then signed lane butterflies ----
    float F[16];
    #pragma unroll
    for (int i = 0; i < 16; ++i) { f2 t = s[i] * s[i]; F[i] = t.x + t.y; }
    #pragma unroll
    for (int bit = 1; bit < 16; bit <<= 1) {
        #pragma unroll
        for (int i = 0; i < 16; ++i)
            if (!(i & bit)) { float u = F[i], v = F[i | bit]; F[i] = u + v; F[i | bit] = u - v; }
    }
    float ow = 0.0f;
    #pragma unroll
    for (int qi = 0; qi < NQ; ++qi) {
        const unsigned m = TAB.mr[qi];
        const unsigned ml = m & 15u, mh = m >> 4;
        float v = F[ml];
        if (mh) {
            unsigned sg = (unsigned)(__builtin_popcount((unsigned)lane & mh) & 1) << 31;
            v = __uint_as_float(__float_as_uint(v) ^ sg);
        }
        v += lxf<1u>(v); v += lxf<2u>(v); v += lxf<4u>(v);
        v += lxf<8u>(v); v += lxf<16u>(v); v += lxf<32u>(v);
        ow = (lane == qi) ? v : ow;
    }
    if (lane < NQ) out[b * NQ + lane] = ow;
}

extern "C" void kernel_launch(void* const* d_in, const int* in_sizes, int n_in,
                              void* d_out, int out_size, void* d_ws, size_t ws_size,
                              hipStream_t stream) {
    const float* inp = (const float*)d_in[0];       // (B, NQ) float32
    const float* qw  = (const float*)d_in[1];       // (DEPTH, NQ, 3) float32
    float* out = (float*)d_out;                     // (B, NQ) float32
    float* gates = (float*)d_ws;                    // DEPTH*NQ float4

    const int B = in_sizes[0] / NQ;

    qgate_precompute<<<1, 64, 0, stream>>>(qw, gates);
    qsim_kernel<<<(B + 3) / 4, 256, 0, stream>>>(inp, gates, out, B);
}

// Round 4
// 109.392 us; speedup vs baseline: 4.3060x; 1.2509x over previous
//
#include <hip/hip_runtime.h>

#define NQ 10
#define DEPTH 4

typedef float f2 __attribute__((ext_vector_type(2)));

__device__ __forceinline__ f2 ff(float a, float b) { f2 r; r.x = a; r.y = b; return r; }
__device__ __forceinline__ f2 fsplat(float a) { return ff(a, a); }
__device__ __forceinline__ f2 rot90(f2 a) { return ff(-a.y, a.x); }   // i * a
__device__ __forceinline__ f2 ffma(f2 a, f2 b, f2 c) { return __builtin_elementwise_fma(a, b, c); }
__device__ __forceinline__ f2 cmul(f2 a, f2 b) { return ffma(fsplat(a.x), b, fsplat(a.y) * rot90(b)); }

// ---------------------------------------------------------------------------
// Compile-time GF(2) frame tracking (validated rounds 2-3).
// Storage index s; logical index k = A s. Gate on logical qubit q pairs
// storage s and s^v (v = col q of A^-1), sign = parity(s & row_q(A)).
// ---------------------------------------------------------------------------
struct GateTab {
    unsigned v[DEPTH][NQ];
    unsigned r[DEPTH][NQ];
    unsigned mr[NQ];
};

constexpr GateTab build_tab() {
    GateTab t{};
    unsigned A[NQ], B[NQ];
    for (int p = 0; p < NQ; ++p) { A[p] = 1u << p; B[p] = 1u << p; }
    for (int l = 0; l < DEPTH; ++l) {
        for (int w = 0; w < NQ; ++w) {
            int q = NQ - 1 - w;
            unsigned v = 0;
            for (int p = 0; p < NQ; ++p) v |= ((B[p] >> q) & 1u) << p;
            t.v[l][w] = v;
            t.r[l][w] = A[q];
        }
        int r = (l % (NQ - 1)) + 1;
        for (int w = 0; w < NQ; ++w) {
            int pc = NQ - 1 - w;
            int pt = NQ - 1 - ((w + r) % NQ);
            A[pt] ^= A[pc];
        }
        for (int w = 0; w < NQ; ++w) {
            int pc = NQ - 1 - w;
            int pt = NQ - 1 - ((w + r) % NQ);
            for (int i = 0; i < NQ; ++i) B[i] ^= ((B[i] >> pt) & 1u) << pc;
        }
    }
    for (int i = 0; i < NQ; ++i) t.mr[i] = A[NQ - 1 - i];
    return t;
}
constexpr GateTab TAB = build_tab();

constexpr int msb4(unsigned x) { return (x & 8u) ? 3 : ((x & 4u) ? 2 : ((x & 2u) ? 1 : 0)); }

// ---------------------------------------------------------------------------
// Cross-lane xor exchange: DPP for 1,2,8 (VALU); ds_swizzle for other <32;
// shfl_xor (bpermute) for masks with lane bit 5.
// ---------------------------------------------------------------------------
template<unsigned M>
__device__ __forceinline__ float lxf(float v) {
    if constexpr (M == 1u)
        return __int_as_float(__builtin_amdgcn_update_dpp(__float_as_int(v), __float_as_int(v), 0xB1, 0xF, 0xF, false));
    else if constexpr (M == 2u)
        return __int_as_float(__builtin_amdgcn_update_dpp(__float_as_int(v), __float_as_int(v), 0x4E, 0xF, 0xF, false));
    else if constexpr (M == 8u)
        return __int_as_float(__builtin_amdgcn_update_dpp(__float_as_int(v), __float_as_int(v), 0x128, 0xF, 0xF, false));
    else if constexpr (M < 32u)
        return __int_as_float(__builtin_amdgcn_ds_swizzle(__float_as_int(v), (int)((M << 10) | 0x1Fu)));
    else
        return __shfl_xor(v, (int)M, 64);
}
template<unsigned M>
__device__ __forceinline__ f2 exch(f2 v) { return ff(lxf<M>(v.x), lxf<M>(v.y)); }

// ---------------------------------------------------------------------------
// RY gate along frame direction: amp'_k = c*amp_k + sigma_k*s*amp_{k^v},
// sigma_k = +1 if parity(k & r) else -1. Real coefficients: 2 f2-ops/amp.
// ---------------------------------------------------------------------------
template<int L, int W>
__device__ __forceinline__ void gate_ry(f2* s, const f2* __restrict__ ry, int lane) {
    constexpr unsigned V = TAB.v[L][W], R = TAB.r[L][W];
    constexpr unsigned VL = V & 15u, VH = V >> 4;
    constexpr unsigned RL = R & 15u, RH = R >> 4;
    constexpr unsigned PVR = (unsigned)(__builtin_popcount(VH & RH) & 1);
    const f2 cs = ry[L * NQ + W];      // uniform -> scalar load
    const float c = cs.x;
    float sv = cs.y;
    if constexpr (RH != 0u) {
        unsigned sg = (unsigned)(__builtin_popcount((unsigned)lane & RH) & 1) << 31;
        sv = __uint_as_float(__float_as_uint(sv) ^ sg);
    }
    if constexpr (VH == 0u) {
        constexpr int PV = 1 << msb4(VL);
        #pragma unroll
        for (int i = 0; i < 16; ++i) {
            if (i & PV) continue;
            const int j = i ^ (int)VL;
            const bool pi = __builtin_popcount((unsigned)i & RL) & 1;   // compile-time
            const float ci = pi ? sv : -sv;
            f2 ni = ffma(fsplat(c), s[i], fsplat(ci) * s[j]);
            f2 nj = ffma(fsplat(c), s[j], fsplat(-ci) * s[i]);
            s[i] = ni; s[j] = nj;
        }
    } else if constexpr (VL == 0u) {
        #pragma unroll
        for (int i = 0; i < 16; ++i) {
            const bool pi = __builtin_popcount((unsigned)i & RL) & 1;
            f2 p = exch<VH>(s[i]);   // lockstep: pre-update values everywhere
            s[i] = ffma(fsplat(c), s[i], fsplat(pi ? sv : -sv) * p);
        }
    } else {
        constexpr int PV = 1 << msb4(VL);
        #pragma unroll
        for (int i = 0; i < 16; ++i) {
            if (i & PV) continue;
            const int j = i ^ (int)VL;
            const bool pi = __builtin_popcount((unsigned)i & RL) & 1;
            const bool pj = (!pi) ^ (bool)PVR;   // parity(V&R)==1 identity
            f2 xj = exch<VH>(s[j]);
            f2 xi = exch<VH>(s[i]);
            f2 ni = ffma(fsplat(c), s[i], fsplat(pi ? sv : -sv) * xj);
            f2 nj = ffma(fsplat(c), s[j], fsplat(pj ? sv : -sv) * xi);
            s[i] = ni; s[j] = nj;
        }
    }
}

template<int L, int W> struct Seq {
    static __device__ __forceinline__ void run(f2* s, const f2* ry, int lane) {
        gate_ry<L, W>(s, ry, lane);
        Seq<L, W + 1>::run(s, ry, lane);
    }
};
template<int L> struct Seq<L, NQ> {
    static __device__ __forceinline__ void run(f2*, const f2*, int) {}
};

// ---------------------------------------------------------------------------
// Workspace layout (floats): [0,40) layer-0 Rot float4 x10; [64,144) RY (c,s)
// f2 x40 (entries 10..39); [256,6400) diag tables f2[3][1024], entry for
// storage k at [gap][k&15][k>>4] (coalesced main-kernel loads).
// ---------------------------------------------------------------------------
__global__ __launch_bounds__(1024) void qprep(const float* __restrict__ qw,
                                              float* __restrict__ ws) {
    const int k = threadIdx.x;
    float4* g0 = (float4*)ws;
    f2* ry = (f2*)(ws + 64);
    f2* dg = (f2*)(ws + 256);

    if (k < NQ) {   // full Rot for layer 0 (fused into init)
        float phi = qw[k*3+0], theta = qw[k*3+1], omega = qw[k*3+2];
        float s, c;   sincosf(0.5f * theta, &s, &c);
        float sa, ca; sincosf(0.5f * (phi + omega), &sa, &ca);
        float sb, cb; sincosf(0.5f * (phi - omega), &sb, &cb);
        g0[k] = make_float4(c * ca, -c * sa, -s * cb, -s * sb);
    } else if (k >= 16 && k < 16 + 3 * NQ) {   // RY coefficients layers 1..3
        int g = k - 6;                          // gate index 10..39
        float theta = qw[g * 3 + 1];
        float s, c; sincosf(0.5f * theta, &s, &c);
        ry[g] = ff(c, s);
    }

    // merged diagonal phases per storage index k
    // gap0 = phi(L1); gap1 = omega(L1)+phi(L2); gap2 = omega(L2)+phi(L3).
    // RZ(a): logical bit b contributes (b ? +a/2 : -a/2); b = parity(k & r).
    float ph0 = 0.f, ph1 = 0.f, ph2 = 0.f;
    #pragma unroll
    for (int w = 0; w < NQ; ++w) {
        const float s1 = (__builtin_popcount((unsigned)k & TAB.r[1][w]) & 1) ? 0.5f : -0.5f;
        const float s2 = (__builtin_popcount((unsigned)k & TAB.r[2][w]) & 1) ? 0.5f : -0.5f;
        const float s3 = (__builtin_popcount((unsigned)k & TAB.r[3][w]) & 1) ? 0.5f : -0.5f;
        ph0 += s1 * qw[(1 * NQ + w) * 3 + 0];
        ph1 += s1 * qw[(1 * NQ + w) * 3 + 2] + s2 * qw[(2 * NQ + w) * 3 + 0];
        ph2 += s2 * qw[(2 * NQ + w) * 3 + 2] + s3 * qw[(3 * NQ + w) * 3 + 0];
    }
    const int loc = k & 15, ln = k >> 4;
    {
        float s, c;
        sincosf(ph0, &s, &c); dg[0 * 1024 + loc * 64 + ln] = ff(c, s);
        sincosf(ph1, &s, &c); dg[1 * 1024 + loc * 64 + ln] = ff(c, s);
        sincosf(ph2, &s, &c); dg[2 * 1024 + loc * 64 + ln] = ff(c, s);
    }
}

__device__ __forceinline__ void load_diag(f2* d, const f2* __restrict__ base) {
    #pragma unroll
    for (int i = 0; i < 16; ++i) d[i] = base[i * 64];
}
__device__ __forceinline__ void apply_diag(f2* s, const f2* d) {
    #pragma unroll
    for (int i = 0; i < 16; ++i) s[i] = cmul(d[i], s[i]);
}

// ---------------------------------------------------------------------------
// One wave per batch element; 16 complex amps (f2) per lane.
// storage k = (lane << 4) | loc.  qubit w <-> storage bit 9-w.
// ---------------------------------------------------------------------------
__global__ __launch_bounds__(256) void qsim_kernel(
        const float* __restrict__ inp,
        const float* __restrict__ ws,
        float* __restrict__ out,
        int B) {
    const int lane = threadIdx.x & 63;
    int b = (blockIdx.x << 2) | (threadIdx.x >> 6);
    b = __builtin_amdgcn_readfirstlane(b);
    if (b >= B) return;

    const float4* g0 = (const float4*)ws;
    const f2* ry = (const f2*)(ws + 64);
    const f2* dg = (const f2*)(ws + 256);

    // prefetch gap0 diagonal
    f2 d[16];
    load_diag(d, dg + lane);

    // ---- embedding fused with layer-0 Rot; lane w<10 computes qubit w ----
    float x = (lane < NQ) ? inp[b * NQ + lane] : 0.0f;
    float sn, cn;
    sincosf(0.5f * x, &sn, &cn);
    float a0r = 0.f, a0i = 0.f, a1r = 0.f, a1i = 0.f;
    if (lane < NQ) {
        float4 mm = g0[lane];
        a0r = mm.x * cn + mm.z * sn;
        a0i = mm.y * cn + mm.w * sn;
        a1r = -mm.z * cn + mm.x * sn;
        a1i =  mm.w * cn - mm.y * sn;
    }
    f2 L;
    {
        float r0 = __shfl(a0r, 0, 64), i0 = __shfl(a0i, 0, 64);
        float r1 = __shfl(a1r, 0, 64), i1 = __shfl(a1i, 0, 64);
        int bit = (lane >> 5) & 1;
        L = ff(bit ? r1 : r0, bit ? i1 : i0);
    }
    #pragma unroll
    for (int w = 1; w < 6; ++w) {
        float r0 = __shfl(a0r, w, 64), i0 = __shfl(a0i, w, 64);
        float r1 = __shfl(a1r, w, 64), i1 = __shfl(a1i, w, 64);
        int bit = (lane >> (5 - w)) & 1;
        L = cmul(L, ff(bit ? r1 : r0, bit ? i1 : i0));
    }
    f2 A0[4], A1[4];
    #pragma unroll
    for (int j = 0; j < 4; ++j) {
        A0[j] = ff(__shfl(a0r, 6 + j, 64), __shfl(a0i, 6 + j, 64));
        A1[j] = ff(__shfl(a1r, 6 + j, 64), __shfl(a1i, 6 + j, 64));
    }
    f2 s[16];
    {
        f2 t01[4], t23[4], lt[4];
        #pragma unroll
        for (int i = 0; i < 4; ++i) {
            t01[i] = cmul((i & 2) ? A1[0] : A0[0], (i & 1) ? A1[1] : A0[1]);
            t23[i] = cmul((i & 2) ? A1[2] : A0[2], (i & 1) ? A1[3] : A0[3]);
        }
        #pragma unroll
        for (int i = 0; i < 4; ++i) lt[i] = cmul(L, t01[i]);
        #pragma unroll
        for (int i = 0; i < 16; ++i) s[i] = cmul(lt[i >> 2], t23[i & 3]);
    }

    // ---- D(phi1) ; RY1 ; D(w1+phi2) ; RY2 ; D(w2+phi3) ; RY3 ----
    apply_diag(s, d);
    load_diag(d, dg + 1024 + lane);
    Seq<1, 0>::run(s, ry, lane);
    apply_diag(s, d);
    load_diag(d, dg + 2048 + lane);
    Seq<2, 0>::run(s, ry, lane);
    apply_diag(s, d);
    Seq<3, 0>::run(s, ry, lane);
    // omega(L3) diagonal dropped: killed by |amp|^2.

    // ---- measurement: local 16-pt WHT, then signed lane butterflies ----
    float F[16];
    #pragma unroll
    for (int i = 0; i < 16; ++i) { f2 t = s[i] * s[i]; F[i] = t.x + t.y; }
    #pragma unroll
    for (int bit = 1; bit < 16; bit <<= 1) {
        #pragma unroll
        for (int i = 0; i < 16; ++i)
            if (!(i & bit)) { float u = F[i], v = F[i | bit]; F[i] = u + v; F[i | bit] = u - v; }
    }
    float ow = 0.0f;
    #pragma unroll
    for (int qi = 0; qi < NQ; ++qi) {
        const unsigned m = TAB.mr[qi];
        const unsigned ml = m & 15u, mh = m >> 4;
        float v = F[ml];
        if (mh) {
            unsigned sg = (unsigned)(__builtin_popcount((unsigned)lane & mh) & 1) << 31;
            v = __uint_as_float(__float_as_uint(v) ^ sg);
        }
        v += lxf<1u>(v); v += lxf<2u>(v); v += lxf<4u>(v);
        v += lxf<8u>(v); v += lxf<16u>(v); v += lxf<32u>(v);
        ow = (lane == qi) ? v : ow;
    }
    if (lane < NQ) out[b * NQ + lane] = ow;
}

extern "C" void kernel_launch(void* const* d_in, const int* in_sizes, int n_in,
                              void* d_out, int out_size, void* d_ws, size_t ws_size,
                              hipStream_t stream) {
    const float* inp = (const float*)d_in[0];       // (B, NQ) float32
    const float* qw  = (const float*)d_in[1];       // (DEPTH, NQ, 3) float32
    float* out = (float*)d_out;                     // (B, NQ) float32
    float* ws  = (float*)d_ws;                      // 25600 B used

    const int B = in_sizes[0] / NQ;

    qprep<<<1, 1024, 0, stream>>>(qw, ws);
    qsim_kernel<<<(B + 3) / 4, 256, 0, stream>>>(inp, ws, out, B);
}